// Round 1
// baseline (683.320 us; speedup 1.0000x reference)
//
#include <hip/hip_runtime.h>

// Problem constants (from reference): N=E=100000, NNZ=800000, R=4, F=64.
static constexpr int F = 64;      // feature dim
static constexpr int RF = 256;    // R*F, row stride of output

// Step 1: he_feat[c] += x[rows[k]] * vals[k], staged into out[:, 3, :]
// (he_feat is E x F; E == N so it exactly fits the r=3 slice of out,
//  which gets overwritten with x at the end anyway).
__global__ void k_hefeat(const float* __restrict__ x,
                         const float* __restrict__ vals,
                         const int* __restrict__ rows,
                         const int* __restrict__ cols,
                         float* __restrict__ out, int nnz)
{
    int t = blockIdx.x * 256 + threadIdx.x;
    int k = t >> 6;           // one nnz per 64-lane group
    if (k >= nnz) return;
    int f = t & 63;
    int rw = rows[k];
    int c  = cols[k];
    float v = vals[k];
    // coalesced 256B read of x row, scatter-atomic into he_feat slice
    atomicAdd(out + (size_t)c * RF + 3 * F + f,
              x[(size_t)rw * F + f] * v);
}

// Step 2: seq[n, r, :] += rank_masks[r][he_idxs[e]] * he_feat[e] * vals[k]
// for r = 0..2 only (r=3 is overwritten by x afterwards).
__global__ void k_seq(const float* __restrict__ rank_masks,
                      const float* __restrict__ vals,
                      const int* __restrict__ he_idxs,
                      const int* __restrict__ rows,
                      const int* __restrict__ cols,
                      float* __restrict__ out, int nnz, int E)
{
    int t = blockIdx.x * 256 + threadIdx.x;
    int k = t >> 6;
    if (k >= nnz) return;
    int f = t & 63;
    int n = rows[k];
    int e = cols[k];
    float v = vals[k];
    int idx = he_idxs[e];                       // wave-uniform scalar gather
    float hf = out[(size_t)e * RF + 3 * F + f] * v;  // he_feat[e][f]
    float w0 = rank_masks[idx];
    float w1 = rank_masks[(size_t)E + idx];
    float w2 = rank_masks[2 * (size_t)E + idx];
    float* base = out + (size_t)n * RF + f;
    atomicAdd(base + 0 * F, w0 * hf);
    atomicAdd(base + 1 * F, w1 * hf);
    atomicAdd(base + 2 * F, w2 * hf);
}

// Step 3: out[:, 3, :] = x  (overwrites the he_feat staging slice).
__global__ void k_lastrank(const float* __restrict__ x,
                           float* __restrict__ out, int n_nodes)
{
    int t = blockIdx.x * 256 + threadIdx.x;
    int n = t >> 6;
    if (n >= n_nodes) return;
    int f = t & 63;
    out[(size_t)n * RF + 3 * F + f] = x[(size_t)n * F + f];
}

extern "C" void kernel_launch(void* const* d_in, const int* in_sizes, int n_in,
                              void* d_out, int out_size, void* d_ws, size_t ws_size,
                              hipStream_t stream)
{
    const float* x       = (const float*)d_in[0];
    const float* rm      = (const float*)d_in[1];
    const float* vals    = (const float*)d_in[2];
    const int*   he_idxs = (const int*)d_in[3];
    const int*   rows    = (const int*)d_in[4];
    const int*   cols    = (const int*)d_in[5];
    float* out = (float*)d_out;

    const int nnz = in_sizes[2];          // 800000
    const int E   = in_sizes[3];          // 100000
    const int nN  = in_sizes[0] / F;      // 100000

    // Zero the accumulators (harness poisons d_out with 0xAA; also required
    // for determinism across graph replays).
    hipMemsetAsync(d_out, 0, (size_t)out_size * sizeof(float), stream);

    const int nnz_blocks = (nnz * 64 + 255) / 256;
    k_hefeat<<<nnz_blocks, 256, 0, stream>>>(x, vals, rows, cols, out, nnz);
    k_seq<<<nnz_blocks, 256, 0, stream>>>(rm, vals, he_idxs, rows, cols, out, nnz, E);

    const int node_blocks = (nN * 64 + 255) / 256;
    k_lastrank<<<node_blocks, 256, 0, stream>>>(x, out, nN);
}

// Round 2
// 511.570 us; speedup vs baseline: 1.3357x; 1.3357x over previous
//
#include <hip/hip_runtime.h>

// Problem constants (from reference): N=E=100000, NNZ=800000, R=4, F=64.
static constexpr int F  = 64;    // feature dim
static constexpr int RF = 256;   // R*F, row stride of output

// ---------------------------------------------------------------------------
// CSR build: histogram -> 2-level exclusive scan -> slot scatter
// ---------------------------------------------------------------------------

// Histogram both axes in one pass over the COO list.
__global__ void k_hist(const int* __restrict__ rows, const int* __restrict__ cols,
                       int* __restrict__ row_cnt, int* __restrict__ col_cnt, int nnz)
{
    int t = blockIdx.x * 256 + threadIdx.x;
    if (t >= nnz) return;
    atomicAdd(&col_cnt[cols[t]], 1);
    atomicAdd(&row_cnt[rows[t]], 1);
}

// Block-level exclusive scan (256/block); writes block totals.
__global__ void k_scan1(int* __restrict__ data, int* __restrict__ blksum, int nseg)
{
    __shared__ int s[256];
    int t = threadIdx.x;
    int i = blockIdx.x * 256 + t;
    int v = (i < nseg) ? data[i] : 0;
    s[t] = v;
    __syncthreads();
    for (int off = 1; off < 256; off <<= 1) {
        int add = (t >= off) ? s[t - off] : 0;
        __syncthreads();
        s[t] += add;
        __syncthreads();
    }
    int inc = s[t];
    if (i < nseg) data[i] = inc - v;       // exclusive within block
    if (t == 255) blksum[blockIdx.x] = inc;
}

// Single-block scan of block sums (supports up to 512 blocks = 131072 segs).
__global__ void k_scan2(const int* __restrict__ blksum, int* __restrict__ blkoff, int nb)
{
    __shared__ int s[512];
    int t = threadIdx.x;
    int v = (t < nb) ? blksum[t] : 0;
    s[t] = v;
    __syncthreads();
    for (int off = 1; off < 512; off <<= 1) {
        int add = (t >= off) ? s[t - off] : 0;
        __syncthreads();
        s[t] += add;
        __syncthreads();
    }
    if (t < nb) blkoff[t] = s[t] - v;      // exclusive
}

// Add block offsets; init scatter cursors; set ptr[nseg]=total.
__global__ void k_scan3(int* __restrict__ data, const int* __restrict__ blkoff,
                        int* __restrict__ cur, int nseg, int total)
{
    int i = blockIdx.x * 256 + threadIdx.x;
    if (i >= nseg) return;
    int p = data[i] + blkoff[i >> 8];
    data[i] = p;
    cur[i]  = p;
    if (i == 0) data[nseg] = total;
}

// Scatter nnz indices into both CSR index arrays.
__global__ void k_scatter(const int* __restrict__ rows, const int* __restrict__ cols,
                          int* __restrict__ row_cur, int* __restrict__ col_cur,
                          int* __restrict__ row_idx, int* __restrict__ col_idx, int nnz)
{
    int t = blockIdx.x * 256 + threadIdx.x;
    if (t >= nnz) return;
    int cs = atomicAdd(&col_cur[cols[t]], 1);
    col_idx[cs] = t;
    int rs = atomicAdd(&row_cur[rows[t]], 1);
    row_idx[rs] = t;
}

// ---------------------------------------------------------------------------
// Gather phase (atomic-free)
// ---------------------------------------------------------------------------

// he_feat[e][f] = sum over members: x[rows[k]][f]*vals[k]; staged in out[:,3,:].
__global__ void k_hefeat_gather(const float* __restrict__ x,
                                const float* __restrict__ vals,
                                const int* __restrict__ rows,
                                const int* __restrict__ col_ptr,
                                const int* __restrict__ col_idx,
                                float* __restrict__ out, int E)
{
    int wave = threadIdx.x >> 6, f = threadIdx.x & 63;
    int e = blockIdx.x * 4 + wave;
    if (e >= E) return;
    int beg = col_ptr[e], end = col_ptr[e + 1];
    float acc = 0.f;
    for (int j = beg; j < end; ++j) {
        int k  = col_idx[j];      // wave-uniform
        int rw = rows[k];
        float v = vals[k];
        acc += x[(size_t)rw * F + f] * v;   // coalesced 256B row read
    }
    out[(size_t)e * RF + 3 * F + f] = acc;
}

// seq[n][r][f] = sum over incident edges: rank_masks[r][he_idxs[e]]*he_feat[e][f]*vals[k]
__global__ void k_seq_gather(const float* __restrict__ rank_masks,
                             const float* __restrict__ vals,
                             const int* __restrict__ he_idxs,
                             const int* __restrict__ cols,
                             const int* __restrict__ row_ptr,
                             const int* __restrict__ row_idx,
                             float* __restrict__ out, int Nn, int E)
{
    int wave = threadIdx.x >> 6, f = threadIdx.x & 63;
    int n = blockIdx.x * 4 + wave;
    if (n >= Nn) return;
    int beg = row_ptr[n], end = row_ptr[n + 1];
    float a0 = 0.f, a1 = 0.f, a2 = 0.f;
    for (int j = beg; j < end; ++j) {
        int k = row_idx[j];       // wave-uniform chain
        int e = cols[k];
        float v = vals[k];
        int idx = he_idxs[e];
        float hf = out[(size_t)e * RF + 3 * F + f] * v;  // he_feat row, coalesced
        a0 += rank_masks[idx] * hf;
        a1 += rank_masks[(size_t)E + idx] * hf;
        a2 += rank_masks[2 * (size_t)E + idx] * hf;
    }
    float* base = out + (size_t)n * RF + f;
    base[0 * F] = a0;
    base[1 * F] = a1;
    base[2 * F] = a2;
}

// out[:, 3, :] = x  (overwrites the he_feat staging slice; last phase).
__global__ void k_lastrank(const float* __restrict__ x,
                           float* __restrict__ out, int n_nodes)
{
    int t = blockIdx.x * 256 + threadIdx.x;
    int n = t >> 6;
    if (n >= n_nodes) return;
    int f = t & 63;
    out[(size_t)n * RF + 3 * F + f] = x[(size_t)n * F + f];
}

// ---------------------------------------------------------------------------
// Fallback (round-1 atomic path) in case ws_size is too small for CSR.
// ---------------------------------------------------------------------------
__global__ void k_hefeat_atomic(const float* __restrict__ x,
                                const float* __restrict__ vals,
                                const int* __restrict__ rows,
                                const int* __restrict__ cols,
                                float* __restrict__ out, int nnz)
{
    int t = blockIdx.x * 256 + threadIdx.x;
    int k = t >> 6;
    if (k >= nnz) return;
    int f = t & 63;
    atomicAdd(out + (size_t)cols[k] * RF + 3 * F + f,
              x[(size_t)rows[k] * F + f] * vals[k]);
}

__global__ void k_seq_atomic(const float* __restrict__ rank_masks,
                             const float* __restrict__ vals,
                             const int* __restrict__ he_idxs,
                             const int* __restrict__ rows,
                             const int* __restrict__ cols,
                             float* __restrict__ out, int nnz, int E)
{
    int t = blockIdx.x * 256 + threadIdx.x;
    int k = t >> 6;
    if (k >= nnz) return;
    int f = t & 63;
    int n = rows[k], e = cols[k];
    float v = vals[k];
    int idx = he_idxs[e];
    float hf = out[(size_t)e * RF + 3 * F + f] * v;
    float* base = out + (size_t)n * RF + f;
    atomicAdd(base + 0 * F, rank_masks[idx] * hf);
    atomicAdd(base + 1 * F, rank_masks[(size_t)E + idx] * hf);
    atomicAdd(base + 2 * F, rank_masks[2 * (size_t)E + idx] * hf);
}

// ---------------------------------------------------------------------------

extern "C" void kernel_launch(void* const* d_in, const int* in_sizes, int n_in,
                              void* d_out, int out_size, void* d_ws, size_t ws_size,
                              hipStream_t stream)
{
    const float* x       = (const float*)d_in[0];
    const float* rm      = (const float*)d_in[1];
    const float* vals    = (const float*)d_in[2];
    const int*   he_idxs = (const int*)d_in[3];
    const int*   rows    = (const int*)d_in[4];
    const int*   cols    = (const int*)d_in[5];
    float* out = (float*)d_out;

    const int nnz = in_sizes[2];          // 800000
    const int E   = in_sizes[3];          // 100000
    const int nN  = in_sizes[0] / F;      // 100000

    const int NBc = (E + 255) / 256;      // scan blocks for cols
    const int NBr = (nN + 255) / 256;     // scan blocks for rows

    // d_ws layout (ints)
    size_t off = 0;
    int* col_ptr = (int*)d_ws + off; off += (size_t)E + 1;   // cnt -> ptr
    int* row_ptr = (int*)d_ws + off; off += (size_t)nN + 1;  // cnt -> ptr
    int* col_idx = (int*)d_ws + off; off += nnz;
    int* row_idx = (int*)d_ws + off; off += nnz;
    int* col_cur = (int*)d_ws + off; off += E;
    int* row_cur = (int*)d_ws + off; off += nN;
    int* bs_c    = (int*)d_ws + off; off += NBc;
    int* bs_r    = (int*)d_ws + off; off += NBr;
    int* bo_c    = (int*)d_ws + off; off += NBc;
    int* bo_r    = (int*)d_ws + off; off += NBr;
    const size_t need = off * sizeof(int);

    const int nnz_blocks  = (nnz + 255) / 256;
    const int seg_blocks  = (E + 3) / 4;           // 4 waves/block gather
    const int node_blocks = (nN + 3) / 4;
    const int lr_blocks   = (nN * F + 255) / 256;

    if (ws_size >= need && NBc <= 512 && NBr <= 512) {
        // --- CSR build ---
        hipMemsetAsync(d_ws, 0, ((size_t)E + nN + 2) * sizeof(int), stream);
        k_hist<<<nnz_blocks, 256, 0, stream>>>(rows, cols, row_ptr, col_ptr, nnz);
        k_scan1<<<NBc, 256, 0, stream>>>(col_ptr, bs_c, E);
        k_scan2<<<1, 512, 0, stream>>>(bs_c, bo_c, NBc);
        k_scan3<<<NBc, 256, 0, stream>>>(col_ptr, bo_c, col_cur, E, nnz);
        k_scan1<<<NBr, 256, 0, stream>>>(row_ptr, bs_r, nN);
        k_scan2<<<1, 512, 0, stream>>>(bs_r, bo_r, NBr);
        k_scan3<<<NBr, 256, 0, stream>>>(row_ptr, bo_r, row_cur, nN, nnz);
        k_scatter<<<nnz_blocks, 256, 0, stream>>>(rows, cols, row_cur, col_cur,
                                                  row_idx, col_idx, nnz);
        // --- gather (atomic-free; no output memset needed) ---
        k_hefeat_gather<<<seg_blocks, 256, 0, stream>>>(x, vals, rows,
                                                        col_ptr, col_idx, out, E);
        k_seq_gather<<<node_blocks, 256, 0, stream>>>(rm, vals, he_idxs, cols,
                                                      row_ptr, row_idx, out, nN, E);
        k_lastrank<<<lr_blocks, 256, 0, stream>>>(x, out, nN);
    } else {
        // --- fallback: atomic scatter path ---
        hipMemsetAsync(d_out, 0, (size_t)out_size * sizeof(float), stream);
        const int b64 = (nnz * 64 + 255) / 256;
        k_hefeat_atomic<<<b64, 256, 0, stream>>>(x, vals, rows, cols, out, nnz);
        k_seq_atomic<<<b64, 256, 0, stream>>>(rm, vals, he_idxs, rows, cols, out, nnz, E);
        k_lastrank<<<lr_blocks, 256, 0, stream>>>(x, out, nN);
    }
}

// Round 3
// 264.509 us; speedup vs baseline: 2.5834x; 1.9340x over previous
//
#include <hip/hip_runtime.h>

// Problem constants (from reference): N=E=100000, NNZ=800000, R=4, F=64.
static constexpr int F  = 64;    // feature dim
static constexpr int RF = 256;   // R*F, row stride of output

// ---------------------------------------------------------------------------
// CSR build: histogram -> 2-level exclusive scan -> payload scatter
// ---------------------------------------------------------------------------

__global__ void k_hist(const int* __restrict__ rows, const int* __restrict__ cols,
                       int* __restrict__ row_cnt, int* __restrict__ col_cnt, int nnz)
{
    int t = blockIdx.x * 256 + threadIdx.x;
    if (t >= nnz) return;
    atomicAdd(&col_cnt[cols[t]], 1);
    atomicAdd(&row_cnt[rows[t]], 1);
}

// Block-level exclusive scan (256/block); writes block totals.
__global__ void k_scan1(int* __restrict__ data, int* __restrict__ blksum, int nseg)
{
    __shared__ int s[256];
    int t = threadIdx.x;
    int i = blockIdx.x * 256 + t;
    int v = (i < nseg) ? data[i] : 0;
    s[t] = v;
    __syncthreads();
    for (int off = 1; off < 256; off <<= 1) {
        int add = (t >= off) ? s[t - off] : 0;
        __syncthreads();
        s[t] += add;
        __syncthreads();
    }
    int inc = s[t];
    if (i < nseg) data[i] = inc - v;       // exclusive within block
    if (t == 255) blksum[blockIdx.x] = inc;
}

// Single-block scan of block sums (supports up to 512 blocks = 131072 segs).
__global__ void k_scan2(const int* __restrict__ blksum, int* __restrict__ blkoff, int nb)
{
    __shared__ int s[512];
    int t = threadIdx.x;
    int v = (t < nb) ? blksum[t] : 0;
    s[t] = v;
    __syncthreads();
    for (int off = 1; off < 512; off <<= 1) {
        int add = (t >= off) ? s[t - off] : 0;
        __syncthreads();
        s[t] += add;
        __syncthreads();
    }
    if (t < nb) blkoff[t] = s[t] - v;      // exclusive
}

// Add block offsets; init scatter cursors; set ptr[nseg]=total.
__global__ void k_scan3(int* __restrict__ data, const int* __restrict__ blkoff,
                        int* __restrict__ cur, int nseg, int total)
{
    int i = blockIdx.x * 256 + threadIdx.x;
    if (i >= nseg) return;
    int p = data[i] + blkoff[i >> 8];
    data[i] = p;
    cur[i]  = p;
    if (i == 0) data[nseg] = total;
}

// Scatter per-slot PAYLOADS (collapses the gather-side dependent chain):
//  row side: {w0*v, w1*v, w2*v, e}   (16B)  -- all rank_masks lookups done here
//  col side: {row, v}                 (8B)
__global__ void k_scatter(const int* __restrict__ rows, const int* __restrict__ cols,
                          const float* __restrict__ vals,
                          const int* __restrict__ he_idxs,
                          const float* __restrict__ rm,
                          int* __restrict__ row_cur, int* __restrict__ col_cur,
                          float4* __restrict__ row_pay, int2* __restrict__ col_pay,
                          int nnz, int E)
{
    int t = blockIdx.x * 256 + threadIdx.x;
    if (t >= nnz) return;
    int r = rows[t], c = cols[t];
    float v = vals[t];
    int idx = he_idxs[c];
    float4 p;
    p.x = rm[idx] * v;
    p.y = rm[(size_t)E + idx] * v;
    p.z = rm[2 * (size_t)E + idx] * v;
    p.w = __int_as_float(c);
    int rs = atomicAdd(&row_cur[r], 1);
    row_pay[rs] = p;
    int cs = atomicAdd(&col_cur[c], 1);
    col_pay[cs] = make_int2(r, __float_as_int(v));
}

// ---------------------------------------------------------------------------
// Gather phase: wave = one segment, 4 groups x 16 lanes x float4 = 4 edges/iter
// ---------------------------------------------------------------------------

__device__ inline float4 group_reduce4(float4 a)
{
    a.x += __shfl_xor(a.x, 16); a.y += __shfl_xor(a.y, 16);
    a.z += __shfl_xor(a.z, 16); a.w += __shfl_xor(a.w, 16);
    a.x += __shfl_xor(a.x, 32); a.y += __shfl_xor(a.y, 32);
    a.z += __shfl_xor(a.z, 32); a.w += __shfl_xor(a.w, 32);
    return a;
}

// he_feat[e][:] = sum over members {row,v}: x[row][:]*v ; staged in out[:,3,:].
__global__ void k_hefeat_gather(const float* __restrict__ x,
                                const int* __restrict__ col_ptr,
                                const int2* __restrict__ col_pay,
                                float* __restrict__ out, int E)
{
    int wave = threadIdx.x >> 6, lane = threadIdx.x & 63;
    int g = lane >> 4, li = lane & 15;
    int e = blockIdx.x * 4 + wave;
    if (e >= E) return;
    int beg = col_ptr[e], end = col_ptr[e + 1];
    float4 acc = make_float4(0.f, 0.f, 0.f, 0.f);
    for (int j = beg + g; j < end; j += 4) {
        int2 cp = col_pay[j];                    // 8B wave-group-uniform
        float v = __int_as_float(cp.y);
        float4 xv = ((const float4*)(x + (size_t)cp.x * F))[li];  // 256B/group
        acc.x += v * xv.x; acc.y += v * xv.y;
        acc.z += v * xv.z; acc.w += v * xv.w;
    }
    acc = group_reduce4(acc);
    if (g == 0)
        ((float4*)(out + (size_t)e * RF + 3 * F))[li] = acc;
}

// seq[n][r][:] = sum over incident slots: w_r * he_feat[e][:]  (r = 0..2)
__global__ void k_seq_gather(const int* __restrict__ row_ptr,
                             const float4* __restrict__ row_pay,
                             float* __restrict__ out, int Nn)
{
    int wave = threadIdx.x >> 6, lane = threadIdx.x & 63;
    int g = lane >> 4, li = lane & 15;
    int n = blockIdx.x * 4 + wave;
    if (n >= Nn) return;
    int beg = row_ptr[n], end = row_ptr[n + 1];
    float4 a0 = make_float4(0.f, 0.f, 0.f, 0.f);
    float4 a1 = a0, a2 = a0;
    for (int j = beg + g; j < end; j += 4) {
        float4 rp = row_pay[j];                  // 16B, chain depth 1
        int e = __float_as_int(rp.w);
        float4 h = ((const float4*)(out + (size_t)e * RF + 3 * F))[li];
        a0.x += rp.x * h.x; a0.y += rp.x * h.y; a0.z += rp.x * h.z; a0.w += rp.x * h.w;
        a1.x += rp.y * h.x; a1.y += rp.y * h.y; a1.z += rp.y * h.z; a1.w += rp.y * h.w;
        a2.x += rp.z * h.x; a2.y += rp.z * h.y; a2.z += rp.z * h.z; a2.w += rp.z * h.w;
    }
    a0 = group_reduce4(a0);
    a1 = group_reduce4(a1);
    a2 = group_reduce4(a2);
    if (g == 0) {
        float4* o = (float4*)(out + (size_t)n * RF);
        o[li]      = a0;    // r = 0
        o[16 + li] = a1;    // r = 1
        o[32 + li] = a2;    // r = 2
    }
}

// out[:, 3, :] = x  (overwrites the he_feat staging slice; last phase).
__global__ void k_lastrank(const float* __restrict__ x,
                           float* __restrict__ out, int n_nodes)
{
    int t = blockIdx.x * 256 + threadIdx.x;     // one float4 per thread
    if (t >= n_nodes * 16) return;
    int n = t >> 4, li = t & 15;
    ((float4*)(out + (size_t)n * RF + 3 * F))[li] =
        ((const float4*)(x + (size_t)n * F))[li];
}

// ---------------------------------------------------------------------------
// Fallback (atomic path) in case ws_size is too small for CSR+payloads.
// ---------------------------------------------------------------------------
__global__ void k_hefeat_atomic(const float* __restrict__ x,
                                const float* __restrict__ vals,
                                const int* __restrict__ rows,
                                const int* __restrict__ cols,
                                float* __restrict__ out, int nnz)
{
    int t = blockIdx.x * 256 + threadIdx.x;
    int k = t >> 6;
    if (k >= nnz) return;
    int f = t & 63;
    atomicAdd(out + (size_t)cols[k] * RF + 3 * F + f,
              x[(size_t)rows[k] * F + f] * vals[k]);
}

__global__ void k_seq_atomic(const float* __restrict__ rank_masks,
                             const float* __restrict__ vals,
                             const int* __restrict__ he_idxs,
                             const int* __restrict__ rows,
                             const int* __restrict__ cols,
                             float* __restrict__ out, int nnz, int E)
{
    int t = blockIdx.x * 256 + threadIdx.x;
    int k = t >> 6;
    if (k >= nnz) return;
    int f = t & 63;
    int n = rows[k], e = cols[k];
    float v = vals[k];
    int idx = he_idxs[e];
    float hf = out[(size_t)e * RF + 3 * F + f] * v;
    float* base = out + (size_t)n * RF + f;
    atomicAdd(base + 0 * F, rank_masks[idx] * hf);
    atomicAdd(base + 1 * F, rank_masks[(size_t)E + idx] * hf);
    atomicAdd(base + 2 * F, rank_masks[2 * (size_t)E + idx] * hf);
}

// ---------------------------------------------------------------------------

extern "C" void kernel_launch(void* const* d_in, const int* in_sizes, int n_in,
                              void* d_out, int out_size, void* d_ws, size_t ws_size,
                              hipStream_t stream)
{
    const float* x       = (const float*)d_in[0];
    const float* rm      = (const float*)d_in[1];
    const float* vals    = (const float*)d_in[2];
    const int*   he_idxs = (const int*)d_in[3];
    const int*   rows    = (const int*)d_in[4];
    const int*   cols    = (const int*)d_in[5];
    float* out = (float*)d_out;

    const int nnz = in_sizes[2];          // 800000
    const int E   = in_sizes[3];          // 100000
    const int nN  = in_sizes[0] / F;      // 100000

    const int NBc = (E + 255) / 256;
    const int NBr = (nN + 255) / 256;

    // d_ws layout: 16B payloads first (alignment), then 8B, then ints.
    char* w = (char*)d_ws;
    float4* row_pay = (float4*)w;                 w += (size_t)nnz * sizeof(float4);
    int2*   col_pay = (int2*)w;                   w += (size_t)nnz * sizeof(int2);
    int* col_ptr = (int*)w;                       w += ((size_t)E + 1) * sizeof(int);
    int* row_ptr = (int*)w;                       w += ((size_t)nN + 1) * sizeof(int);
    int* col_cur = (int*)w;                       w += (size_t)E * sizeof(int);
    int* row_cur = (int*)w;                       w += (size_t)nN * sizeof(int);
    int* bs_c    = (int*)w;                       w += (size_t)NBc * sizeof(int);
    int* bs_r    = (int*)w;                       w += (size_t)NBr * sizeof(int);
    int* bo_c    = (int*)w;                       w += (size_t)NBc * sizeof(int);
    int* bo_r    = (int*)w;                       w += (size_t)NBr * sizeof(int);
    const size_t need = (size_t)(w - (char*)d_ws);

    const int nnz_blocks  = (nnz + 255) / 256;
    const int seg_blocks  = (E + 3) / 4;          // 4 waves/block, wave = segment
    const int node_blocks = (nN + 3) / 4;
    const int lr_blocks   = (nN * 16 + 255) / 256;

    if (ws_size >= need && NBc <= 512 && NBr <= 512) {
        // --- CSR build ---
        hipMemsetAsync(col_ptr, 0, ((size_t)E + nN + 2) * sizeof(int), stream);
        k_hist<<<nnz_blocks, 256, 0, stream>>>(rows, cols, row_ptr, col_ptr, nnz);
        k_scan1<<<NBc, 256, 0, stream>>>(col_ptr, bs_c, E);
        k_scan2<<<1, 512, 0, stream>>>(bs_c, bo_c, NBc);
        k_scan3<<<NBc, 256, 0, stream>>>(col_ptr, bo_c, col_cur, E, nnz);
        k_scan1<<<NBr, 256, 0, stream>>>(row_ptr, bs_r, nN);
        k_scan2<<<1, 512, 0, stream>>>(bs_r, bo_r, NBr);
        k_scan3<<<NBr, 256, 0, stream>>>(row_ptr, bo_r, row_cur, nN, nnz);
        k_scatter<<<nnz_blocks, 256, 0, stream>>>(rows, cols, vals, he_idxs, rm,
                                                  row_cur, col_cur,
                                                  row_pay, col_pay, nnz, E);
        // --- gather (atomic-free; no output memset needed) ---
        k_hefeat_gather<<<seg_blocks, 256, 0, stream>>>(x, col_ptr, col_pay, out, E);
        k_seq_gather<<<node_blocks, 256, 0, stream>>>(row_ptr, row_pay, out, nN);
        k_lastrank<<<lr_blocks, 256, 0, stream>>>(x, out, nN);
    } else {
        // --- fallback: atomic scatter path ---
        hipMemsetAsync(d_out, 0, (size_t)out_size * sizeof(float), stream);
        const int b64 = (nnz * 64 + 255) / 256;
        k_hefeat_atomic<<<b64, 256, 0, stream>>>(x, vals, rows, cols, out, nnz);
        k_seq_atomic<<<b64, 256, 0, stream>>>(rm, vals, he_idxs, rows, cols, out, nnz, E);
        const int lrb = (nN * 16 + 255) / 256;
        k_lastrank<<<lrb, 256, 0, stream>>>(x, out, nN);
    }
}